// Round 4
// baseline (729.072 us; speedup 1.0000x reference)
//
#include <hip/hip_runtime.h>
#include <math.h>

#define HID 128
#define NGRAPH 4
#define NSLICE 8          // feature slices of 16 floats; pinned slice -> XCD

typedef int idx_t;
typedef short bf16x8 __attribute__((ext_vector_type(8)));
typedef float f32x4 __attribute__((ext_vector_type(4)));

__device__ inline ushort f2bf(float f) {
  uint u = __float_as_uint(f);
  u += 0x7FFF + ((u >> 16) & 1);   // RNE
  return (ushort)(u >> 16);
}
__device__ inline float bf2f(ushort h) { return __uint_as_float(((uint)h) << 16); }

// swizzled element offset into a [rows][32] ushort LDS tile (16B slots)
__device__ inline int sw(int row, int slot) {
  return (row << 5) + ((slot ^ ((row >> 1) & 3)) << 3);
}

// ---------------- degree histogram ----------------
__global__ __launch_bounds__(256) void k_count(const idx_t* __restrict__ dst,
                                               int* __restrict__ cnt, int E) {
  int e = blockIdx.x * 256 + threadIdx.x;
  if (e < E) atomicAdd(&cnt[dst[e]], 1);
}

// ---------------- hierarchical exclusive scan ----------------
#define SC 1024  // elements per scan block (256 thr x 4)
__global__ __launch_bounds__(256) void k_scan1(const int* __restrict__ cnt,
                                               int* __restrict__ bsum, int n) {
  __shared__ int sh[256];
  int base = blockIdx.x * SC + threadIdx.x * 4;
  int s = 0;
#pragma unroll
  for (int j = 0; j < 4; ++j) { int i = base + j; if (i < n) s += cnt[i]; }
  sh[threadIdx.x] = s;
  __syncthreads();
  for (int o = 128; o > 0; o >>= 1) {
    if (threadIdx.x < o) sh[threadIdx.x] += sh[threadIdx.x + o];
    __syncthreads();
  }
  if (threadIdx.x == 0) bsum[blockIdx.x] = sh[0];
}

__global__ __launch_bounds__(64) void k_scan2(const int* __restrict__ bsum,
                                              int* __restrict__ boff,
                                              int* __restrict__ off, int nb, int n) {
  int lane = threadIdx.x;
  int v = (lane < nb) ? bsum[lane] : 0;
  for (int d = 1; d < 64; d <<= 1) {
    int t = __shfl_up(v, d);
    if (lane >= d) v += t;
  }
  int ex = __shfl_up(v, 1);
  if (lane == 0) ex = 0;
  if (lane < nb) boff[lane] = ex;
  if (lane == nb - 1) off[n] = v;  // grand total
}

__global__ __launch_bounds__(256) void k_scan3(const int* __restrict__ cnt,
                                               const int* __restrict__ boff,
                                               int* __restrict__ off,
                                               float* __restrict__ dinv, int n) {
  __shared__ int sh[256];
  int base = blockIdx.x * SC + threadIdx.x * 4;
  int c[4];
  int s = 0;
#pragma unroll
  for (int j = 0; j < 4; ++j) {
    int i = base + j;
    c[j] = (i < n) ? cnt[i] : 0;
    s += c[j];
  }
  sh[threadIdx.x] = s;
  __syncthreads();
  for (int o = 1; o < 256; o <<= 1) {
    int t = (threadIdx.x >= (unsigned)o) ? sh[threadIdx.x - o] : 0;
    __syncthreads();
    sh[threadIdx.x] += t;
    __syncthreads();
  }
  int ex = sh[threadIdx.x] - s + boff[blockIdx.x];
#pragma unroll
  for (int j = 0; j < 4; ++j) {
    int i = base + j;
    if (i < n) {
      off[i] = ex;
      dinv[i] = 1.0f / sqrtf((float)c[j] + 1.0f);  // deg + self-loop
      ex += c[j];
    }
  }
}

// ---------------- CSR fill: packed (src, weight) per edge ----------------
__global__ __launch_bounds__(256) void k_fill(const idx_t* __restrict__ src,
                                              const idx_t* __restrict__ dst,
                                              const int* __restrict__ off,
                                              const float* __restrict__ dinv,
                                              int* __restrict__ fillc,
                                              int2* __restrict__ edata, int E) {
  int e = blockIdx.x * 256 + threadIdx.x;
  if (e < E) {
    int s = src[e], d = dst[e];
    int p = atomicAdd(&fillc[d], 1);
    float w = dinv[s] * dinv[d];
    edata[off[d] + p] = make_int2(s, __float_as_int(w));
  }
}

// ---------------- W split: fp32 [K][128] -> bf16 hi/lo transposed [128][K] ----
__global__ __launch_bounds__(256) void k_wsplit(const float* __restrict__ W,
                                                ushort* __restrict__ Wh,
                                                ushort* __restrict__ Wl, int K) {
  int i = blockIdx.x * 256 + threadIdx.x;
  if (i >= K * HID) return;
  int k = i >> 7, n = i & 127;
  float f = W[i];
  ushort h = f2bf(f);
  Wh[(size_t)n * K + k] = h;
  Wl[(size_t)n * K + k] = f2bf(f - bf2f(h));
}

// ---------------- split-bf16 MFMA GEMM -----------------------------------
// Y (slice-major [8][N][16]) = X @ W.  X row-major if !SLICED, else [8][N][16].
// 3-pass hi/lo: Ah*Bh + Ah*Bl + Al*Bh  (error ~2^-16 relative)
template <int K, bool SLICED>
__global__ __launch_bounds__(256) void k_gemm_mfma(const float* __restrict__ X,
                                                   const ushort* __restrict__ Wh,
                                                   const ushort* __restrict__ Wl,
                                                   float* __restrict__ Y, int M) {
  __shared__ __align__(16) ushort Ah[128 * 32];
  __shared__ __align__(16) ushort Al[128 * 32];
  __shared__ __align__(16) ushort Bh[128 * 32];
  __shared__ __align__(16) ushort Bl[128 * 32];
  int tid = threadIdx.x;
  int wid = tid >> 6, lane = tid & 63;
  int lrow = lane & 15, kg = lane >> 4;  // frag row/col within 16, k-group 0..3
  int row0 = blockIdx.x * 128;
  size_t sstride = (size_t)M * 16;       // slice stride for sliced layout
  f32x4 acc[2][8] = {};

  for (int k0 = 0; k0 < K; k0 += 32) {
    // stage A: 128 rows x 32 k, fp32 -> bf16 hi/lo in registers
#pragma unroll
    for (int p = 0; p < 2; ++p) {
      int g = tid + (p << 8);       // 0..511
      int r = g >> 2, s = g & 3;    // row, 8-elem slot
      int grow = row0 + r;
      float xv[8] = {0.f, 0.f, 0.f, 0.f, 0.f, 0.f, 0.f, 0.f};
      if (grow < M) {
        const float* src;
        if (SLICED) {
          int q = k0 + s * 8;       // feature index
          src = X + (size_t)(q >> 4) * sstride + (size_t)grow * 16 + (q & 15);
        } else {
          src = X + (size_t)grow * K + k0 + s * 8;
        }
        const float4 v0 = *(const float4*)src;
        const float4 v1 = *(const float4*)(src + 4);
        xv[0] = v0.x; xv[1] = v0.y; xv[2] = v0.z; xv[3] = v0.w;
        xv[4] = v1.x; xv[5] = v1.y; xv[6] = v1.z; xv[7] = v1.w;
      }
      bf16x8 hv, lv;
#pragma unroll
      for (int j = 0; j < 8; ++j) {
        ushort hb = f2bf(xv[j]);
        hv[j] = (short)hb;
        lv[j] = (short)f2bf(xv[j] - bf2f(hb));
      }
      *(bf16x8*)&Ah[sw(r, s)] = hv;
      *(bf16x8*)&Al[sw(r, s)] = lv;
    }
    // stage B: 128 cols x 32 k from pre-split transposed W (bf16)
#pragma unroll
    for (int p = 0; p < 2; ++p) {
      int g = tid + (p << 8);
      int c = g >> 2, s = g & 3;
      *(bf16x8*)&Bh[sw(c, s)] = *(const bf16x8*)&Wh[(size_t)c * K + k0 + s * 8];
      *(bf16x8*)&Bl[sw(c, s)] = *(const bf16x8*)&Wl[(size_t)c * K + k0 + s * 8];
    }
    __syncthreads();

    bf16x8 ah[2], al[2];
#pragma unroll
    for (int mi = 0; mi < 2; ++mi) {
      int r = wid * 32 + mi * 16 + lrow;
      ah[mi] = *(const bf16x8*)&Ah[sw(r, kg)];
      al[mi] = *(const bf16x8*)&Al[sw(r, kg)];
    }
#pragma unroll
    for (int ni = 0; ni < 8; ++ni) {
      int c = ni * 16 + lrow;
      bf16x8 bh = *(const bf16x8*)&Bh[sw(c, kg)];
      bf16x8 bl = *(const bf16x8*)&Bl[sw(c, kg)];
#pragma unroll
      for (int mi = 0; mi < 2; ++mi) {
        acc[mi][ni] = __builtin_amdgcn_mfma_f32_16x16x32_bf16(ah[mi], bh, acc[mi][ni], 0, 0, 0);
        acc[mi][ni] = __builtin_amdgcn_mfma_f32_16x16x32_bf16(al[mi], bh, acc[mi][ni], 0, 0, 0);
        acc[mi][ni] = __builtin_amdgcn_mfma_f32_16x16x32_bf16(ah[mi], bl, acc[mi][ni], 0, 0, 0);
      }
    }
    __syncthreads();
  }
  // epilogue: C frag row=(lane>>4)*4+reg, col=lane&15 -> slice ni, within lrow
#pragma unroll
  for (int mi = 0; mi < 2; ++mi)
#pragma unroll
    for (int ni = 0; ni < 8; ++ni)
#pragma unroll
      for (int r = 0; r < 4; ++r) {
        int grow = row0 + wid * 32 + mi * 16 + kg * 4 + r;
        if (grow < M)
          Y[(size_t)ni * sstride + (size_t)grow * 16 + lrow] = acc[mi][ni][r];
      }
}

// ---------------- sliced gather-aggregate + bias + ReLU ---------------------
// Slice s handled only by blocks with blockIdx%8==s -> lands on one XCD whose
// L2 holds the whole 3.2 MB slice. 4 threads per node cover 16 floats.
__global__ __launch_bounds__(256) void k_agg_s(const float* __restrict__ xs,
                                               const float* __restrict__ dinv,
                                               const int* __restrict__ off,
                                               const int2* __restrict__ edata,
                                               const float* __restrict__ bias,
                                               float* __restrict__ hs, int n) {
  int slice = blockIdx.x & 7;
  int chunk = blockIdx.x >> 3;
  int v = chunk * 64 + (threadIdx.x >> 2);
  if (v >= n) return;
  int qd = (threadIdx.x & 3) << 2;            // 0,4,8,12
  const float* xsl = xs + (size_t)slice * n * 16;
  float dv = dinv[v];
  const float4 self = *(const float4*)&xsl[(size_t)v * 16 + qd];
  float4 acc;
  acc.x = dv * dv * self.x; acc.y = dv * dv * self.y;
  acc.z = dv * dv * self.z; acc.w = dv * dv * self.w;
  int j0 = off[v], j1 = off[v + 1];
  if (j0 < j1) {
    long long ecur = __builtin_nontemporal_load((const long long*)&edata[j0]);
    for (int j = j0; j < j1; ++j) {
      long long enext = (j + 1 < j1)
          ? __builtin_nontemporal_load((const long long*)&edata[j + 1]) : ecur;
      int u = (int)(ecur & 0xFFFFFFFFll);
      float w = __int_as_float((int)(ecur >> 32));
      const float4 m = *(const float4*)&xsl[(size_t)u * 16 + qd];
      acc.x = fmaf(w, m.x, acc.x); acc.y = fmaf(w, m.y, acc.y);
      acc.z = fmaf(w, m.z, acc.z); acc.w = fmaf(w, m.w, acc.w);
      ecur = enext;
    }
  }
  const float4 b = *(const float4*)&bias[slice * 16 + qd];
  float4 o;
  o.x = fmaxf(acc.x + b.x, 0.0f);
  o.y = fmaxf(acc.y + b.y, 0.0f);
  o.z = fmaxf(acc.z + b.z, 0.0f);
  o.w = fmaxf(acc.w + b.w, 0.0f);
  *(float4*)&hs[(size_t)slice * n * 16 + (size_t)v * 16 + qd] = o;
}

// ---------------- per-graph node counts ----------------
__global__ __launch_bounds__(256) void k_gcnt(const idx_t* __restrict__ batch,
                                              int* __restrict__ gcnt, int n) {
  __shared__ int h[NGRAPH];
  int tid = threadIdx.x;
  if (tid < NGRAPH) h[tid] = 0;
  __syncthreads();
  int i = blockIdx.x * 256 + tid;
  if (i < n) atomicAdd(&h[batch[i]], 1);
  __syncthreads();
  if (tid < NGRAPH && h[tid]) atomicAdd(&gcnt[tid], h[tid]);
}

// ---------------- segment max+sum pooling (sliced input, batch sorted) ------
__global__ __launch_bounds__(128) void k_pool(const float* __restrict__ hs,
                                              const idx_t* __restrict__ batch,
                                              float* __restrict__ gmax,
                                              float* __restrict__ gsum, int n) {
  int f = threadIdx.x;
  const float* hp = hs + (size_t)(f >> 4) * n * 16 + (f & 15);
  int v0 = blockIdx.x * 128;
  int cur = -1;
  float mx = 0.f, sm = 0.f;
  for (int i = 0; i < 128; ++i) {
    int v = v0 + i;
    if (v >= n) break;
    int g = batch[v];
    if (g != cur) {
      if (cur >= 0) {
        atomicMax((int*)&gmax[cur * HID + f], __float_as_int(mx));  // h>=0
        atomicAdd(&gsum[cur * HID + f], sm);
      }
      cur = g; mx = 0.f; sm = 0.f;
    }
    float val = hp[(size_t)v * 16];
    mx = fmaxf(mx, val);
    sm += val;
  }
  if (cur >= 0) {
    atomicMax((int*)&gmax[cur * HID + f], __float_as_int(mx));
    atomicAdd(&gsum[cur * HID + f], sm);
  }
}

// ---------------- tiny MLP head (one block) ----------------
__global__ __launch_bounds__(256) void k_mlp(const float* __restrict__ gmax,
                                             const float* __restrict__ gsum,
                                             const int* __restrict__ gcnt,
                                             const float* __restrict__ Wl1,
                                             const float* __restrict__ bl1,
                                             const float* __restrict__ Wl2,
                                             const float* __restrict__ bl2,
                                             const float* __restrict__ Wl3,
                                             const float* __restrict__ bl3,
                                             float* __restrict__ out) {
  __shared__ float G[NGRAPH][2 * HID];
  __shared__ float H1[NGRAPH][HID];
  __shared__ float H2[NGRAPH][HID / 2];
  int t = threadIdx.x;
  for (int i = t; i < NGRAPH * 2 * HID; i += 256) {
    int gi = i >> 8, j = i & 255;
    float val;
    if (j < HID) val = gmax[gi * HID + j];
    else val = gsum[gi * HID + (j - HID)] / fmaxf((float)gcnt[gi], 1.0f);
    G[gi][j] = val;
  }
  __syncthreads();
  for (int i = t; i < NGRAPH * HID; i += 256) {
    int gi = i >> 7, j = i & 127;
    float a = bl1[j];
    for (int k = 0; k < 2 * HID; ++k) a = fmaf(G[gi][k], Wl1[k * HID + j], a);
    H1[gi][j] = fmaxf(a, 0.f);
  }
  __syncthreads();
  {
    int gi = t >> 6, j = t & 63;
    float a = bl2[j];
    for (int k = 0; k < HID; ++k) a = fmaf(H1[gi][k], Wl2[k * 64 + j], a);
    H2[gi][j] = fmaxf(a, 0.f);
  }
  __syncthreads();
  if (t < NGRAPH) {
    float a = bl3[0];
    for (int k = 0; k < 64; ++k) a = fmaf(H2[t][k], Wl3[k], a);
    out[t] = fminf(a, 5.0f);
  }
}

extern "C" void kernel_launch(void* const* d_in, const int* in_sizes, int n_in,
                              void* d_out, int out_size, void* d_ws, size_t ws_size,
                              hipStream_t stream) {
  const float* x   = (const float*)d_in[0];
  const idx_t* ei  = (const idx_t*)d_in[1];
  const idx_t* bat = (const idx_t*)d_in[2];
  const float* W0 = (const float*)d_in[3];  const float* b0 = (const float*)d_in[4];
  const float* W1 = (const float*)d_in[5];  const float* b1 = (const float*)d_in[6];
  const float* W2 = (const float*)d_in[7];  const float* b2 = (const float*)d_in[8];
  const float* Wl1 = (const float*)d_in[9];  const float* bl1 = (const float*)d_in[10];
  const float* Wl2 = (const float*)d_in[11]; const float* bl2 = (const float*)d_in[12];
  const float* Wl3 = (const float*)d_in[13]; const float* bl3 = (const float*)d_in[14];
  float* out = (float*)d_out;

  const int N = in_sizes[2];
  const int E = in_sizes[1] / 2;
  const idx_t* srcv = ei;
  const idx_t* dstv = ei + E;
  const int nb = (N + SC - 1) / SC;  // 49 scan blocks (<=64)

  char* ws = (char*)d_ws;
  size_t o = 0;
  auto alloc = [&](size_t bytes) -> void* {
    void* p = ws + o;
    o = (o + bytes + 255) & ~(size_t)255;
    return p;
  };
  float* xs   = (float*)alloc((size_t)N * HID * 4);   // sliced xw [8][N][16]
  float* hsb  = (float*)alloc((size_t)N * HID * 4);   // sliced h  [8][N][16]
  float* dinv = (float*)alloc((size_t)N * 4);
  int* cnt    = (int*)alloc((size_t)N * 4);
  int* off    = (int*)alloc((size_t)(N + 1) * 4);
  int* fillc  = (int*)alloc((size_t)N * 4);
  int2* edata = (int2*)alloc((size_t)E * 8);
  int* bsum   = (int*)alloc(64 * 4);
  int* boff   = (int*)alloc(64 * 4);
  ushort* Wh0 = (ushort*)alloc((size_t)1024 * HID * 2);
  ushort* Wl0 = (ushort*)alloc((size_t)1024 * HID * 2);
  ushort* Wh1 = (ushort*)alloc((size_t)HID * HID * 2);
  ushort* Wlo1 = (ushort*)alloc((size_t)HID * HID * 2);
  ushort* Wh2 = (ushort*)alloc((size_t)HID * HID * 2);
  ushort* Wlo2 = (ushort*)alloc((size_t)HID * HID * 2);
  float* gmax = (float*)alloc(NGRAPH * HID * 4);
  float* gsum = (float*)alloc(NGRAPH * HID * 4);
  int* gcnt   = (int*)alloc(NGRAPH * 4);

  hipMemsetAsync(cnt, 0, (size_t)N * 4, stream);
  hipMemsetAsync(fillc, 0, (size_t)N * 4, stream);
  hipMemsetAsync(gmax, 0, NGRAPH * HID * 4, stream);
  hipMemsetAsync(gsum, 0, NGRAPH * HID * 4, stream);
  hipMemsetAsync(gcnt, 0, NGRAPH * 4, stream);

  // weight splits (tiny)
  k_wsplit<<<(1024 * HID + 255) / 256, 256, 0, stream>>>(W0, Wh0, Wl0, 1024);
  k_wsplit<<<(HID * HID + 255) / 256, 256, 0, stream>>>(W1, Wh1, Wlo1, HID);
  k_wsplit<<<(HID * HID + 255) / 256, 256, 0, stream>>>(W2, Wh2, Wlo2, HID);

  // CSR build
  k_count<<<(E + 255) / 256, 256, 0, stream>>>(dstv, cnt, E);
  k_scan1<<<nb, 256, 0, stream>>>(cnt, bsum, N);
  k_scan2<<<1, 64, 0, stream>>>(bsum, boff, off, nb, N);
  k_scan3<<<nb, 256, 0, stream>>>(cnt, boff, off, dinv, N);
  k_fill<<<(E + 255) / 256, 256, 0, stream>>>(srcv, dstv, off, dinv, fillc, edata, E);

  const int gblk = (N + 127) / 128;
  const int ablk = ((N + 63) / 64) * NSLICE;
  // layer 0: 1024 -> 128
  k_gemm_mfma<1024, false><<<gblk, 256, 0, stream>>>(x, Wh0, Wl0, xs, N);
  k_agg_s<<<ablk, 256, 0, stream>>>(xs, dinv, off, edata, b0, hsb, N);
  // layer 1
  k_gemm_mfma<HID, true><<<gblk, 256, 0, stream>>>(hsb, Wh1, Wlo1, xs, N);
  k_agg_s<<<ablk, 256, 0, stream>>>(xs, dinv, off, edata, b1, hsb, N);
  // layer 2
  k_gemm_mfma<HID, true><<<gblk, 256, 0, stream>>>(hsb, Wh2, Wlo2, xs, N);
  k_agg_s<<<ablk, 256, 0, stream>>>(xs, dinv, off, edata, b2, hsb, N);

  // pooling + head
  k_gcnt<<<(N + 255) / 256, 256, 0, stream>>>(bat, gcnt, N);
  k_pool<<<(N + 127) / 128, 128, 0, stream>>>(hsb, bat, gmax, gsum, N);
  k_mlp<<<1, 256, 0, stream>>>(gmax, gsum, gcnt, Wl1, bl1, Wl2, bl2, Wl3, bl3, out);
}

// Round 5
// 410.034 us; speedup vs baseline: 1.7781x; 1.7781x over previous
//
#include <hip/hip_runtime.h>
#include <math.h>

#define HID 128
#define NGRAPH 4

typedef int idx_t;
typedef short bf16x8 __attribute__((ext_vector_type(8)));
typedef float f32x4 __attribute__((ext_vector_type(4)));
typedef _Float16 f16x8 __attribute__((ext_vector_type(8)));

__device__ inline ushort f2bf(float f) {
  uint u = __float_as_uint(f);
  u += 0x7FFF + ((u >> 16) & 1);   // RNE
  return (ushort)(u >> 16);
}
__device__ inline float bf2f(ushort h) { return __uint_as_float(((uint)h) << 16); }

// swizzled element offset into a [rows][32] ushort LDS tile (16B slots)
__device__ inline int sw(int row, int slot) {
  return (row << 5) + ((slot ^ ((row >> 1) & 3)) << 3);
}

// ---------------- degree histogram ----------------
__global__ __launch_bounds__(256) void k_count(const idx_t* __restrict__ dst,
                                               int* __restrict__ cnt, int E) {
  int e = blockIdx.x * 256 + threadIdx.x;
  if (e < E) atomicAdd(&cnt[dst[e]], 1);
}

// ---------------- hierarchical exclusive scan ----------------
#define SC 1024  // elements per scan block (256 thr x 4)
__global__ __launch_bounds__(256) void k_scan1(const int* __restrict__ cnt,
                                               int* __restrict__ bsum, int n) {
  __shared__ int sh[256];
  int base = blockIdx.x * SC + threadIdx.x * 4;
  int s = 0;
#pragma unroll
  for (int j = 0; j < 4; ++j) { int i = base + j; if (i < n) s += cnt[i]; }
  sh[threadIdx.x] = s;
  __syncthreads();
  for (int o = 128; o > 0; o >>= 1) {
    if (threadIdx.x < o) sh[threadIdx.x] += sh[threadIdx.x + o];
    __syncthreads();
  }
  if (threadIdx.x == 0) bsum[blockIdx.x] = sh[0];
}

__global__ __launch_bounds__(64) void k_scan2(const int* __restrict__ bsum,
                                              int* __restrict__ boff,
                                              int* __restrict__ off, int nb, int n) {
  int lane = threadIdx.x;
  int v = (lane < nb) ? bsum[lane] : 0;
  for (int d = 1; d < 64; d <<= 1) {
    int t = __shfl_up(v, d);
    if (lane >= d) v += t;
  }
  int ex = __shfl_up(v, 1);
  if (lane == 0) ex = 0;
  if (lane < nb) boff[lane] = ex;
  if (lane == nb - 1) off[n] = v;  // grand total
}

__global__ __launch_bounds__(256) void k_scan3(const int* __restrict__ cnt,
                                               const int* __restrict__ boff,
                                               int* __restrict__ off,
                                               float* __restrict__ dinv, int n) {
  __shared__ int sh[256];
  int base = blockIdx.x * SC + threadIdx.x * 4;
  int c[4];
  int s = 0;
#pragma unroll
  for (int j = 0; j < 4; ++j) {
    int i = base + j;
    c[j] = (i < n) ? cnt[i] : 0;
    s += c[j];
  }
  sh[threadIdx.x] = s;
  __syncthreads();
  for (int o = 1; o < 256; o <<= 1) {
    int t = (threadIdx.x >= (unsigned)o) ? sh[threadIdx.x - o] : 0;
    __syncthreads();
    sh[threadIdx.x] += t;
    __syncthreads();
  }
  int ex = sh[threadIdx.x] - s + boff[blockIdx.x];
#pragma unroll
  for (int j = 0; j < 4; ++j) {
    int i = base + j;
    if (i < n) {
      off[i] = ex;
      dinv[i] = 1.0f / sqrtf((float)c[j] + 1.0f);  // deg + self-loop
      ex += c[j];
    }
  }
}

// ---------------- CSR fill: packed (src, weight) per edge ----------------
__global__ __launch_bounds__(256) void k_fill(const idx_t* __restrict__ src,
                                              const idx_t* __restrict__ dst,
                                              const int* __restrict__ off,
                                              const float* __restrict__ dinv,
                                              int* __restrict__ fillc,
                                              int2* __restrict__ edata, int E) {
  int e = blockIdx.x * 256 + threadIdx.x;
  if (e < E) {
    int s = src[e], d = dst[e];
    int p = atomicAdd(&fillc[d], 1);
    float w = dinv[s] * dinv[d];
    edata[off[d] + p] = make_int2(s, __float_as_int(w));
  }
}

// ---------------- W split: fp32 [K][128] -> bf16 hi/lo transposed [128][K] ----
__global__ __launch_bounds__(256) void k_wsplit(const float* __restrict__ W,
                                                ushort* __restrict__ Wh,
                                                ushort* __restrict__ Wl, int K) {
  int i = blockIdx.x * 256 + threadIdx.x;
  if (i >= K * HID) return;
  int k = i >> 7, n = i & 127;
  float f = W[i];
  ushort h = f2bf(f);
  Wh[(size_t)n * K + k] = h;
  Wl[(size_t)n * K + k] = f2bf(f - bf2f(h));
}

// ---------------- split-bf16 MFMA GEMM: Y[M][128] = X[M][K] @ W[K][128] -----
// 3-pass hi/lo: Ah*Bh + Ah*Bl + Al*Bh (error ~2^-16 rel). Writes fp32 + fp16.
template <int K>
__global__ __launch_bounds__(256) void k_gemm_mfma(const float* __restrict__ X,
                                                   const ushort* __restrict__ Wh,
                                                   const ushort* __restrict__ Wl,
                                                   float* __restrict__ Y,
                                                   _Float16* __restrict__ Y16,
                                                   int M) {
  __shared__ __align__(16) ushort Ah[128 * 32];
  __shared__ __align__(16) ushort Al[128 * 32];
  __shared__ __align__(16) ushort Bh[128 * 32];
  __shared__ __align__(16) ushort Bl[128 * 32];
  int tid = threadIdx.x;
  int wid = tid >> 6, lane = tid & 63;
  int lrow = lane & 15, kg = lane >> 4;  // frag row/col within 16, k-group 0..3
  int row0 = blockIdx.x * 128;
  f32x4 acc[2][8] = {};

  for (int k0 = 0; k0 < K; k0 += 32) {
    // stage A: 128 rows x 32 k, fp32 -> bf16 hi/lo in registers
#pragma unroll
    for (int p = 0; p < 2; ++p) {
      int g = tid + (p << 8);       // 0..511
      int r = g >> 2, s = g & 3;    // row, 8-elem slot
      int grow = row0 + r;
      float xv[8] = {0.f, 0.f, 0.f, 0.f, 0.f, 0.f, 0.f, 0.f};
      if (grow < M) {
        const float4 v0 = *(const float4*)&X[(size_t)grow * K + k0 + s * 8];
        const float4 v1 = *(const float4*)&X[(size_t)grow * K + k0 + s * 8 + 4];
        xv[0] = v0.x; xv[1] = v0.y; xv[2] = v0.z; xv[3] = v0.w;
        xv[4] = v1.x; xv[5] = v1.y; xv[6] = v1.z; xv[7] = v1.w;
      }
      bf16x8 hv, lv;
#pragma unroll
      for (int j = 0; j < 8; ++j) {
        ushort hb = f2bf(xv[j]);
        hv[j] = (short)hb;
        lv[j] = (short)f2bf(xv[j] - bf2f(hb));
      }
      *(bf16x8*)&Ah[sw(r, s)] = hv;
      *(bf16x8*)&Al[sw(r, s)] = lv;
    }
    // stage B: 128 cols x 32 k from pre-split transposed W (bf16)
#pragma unroll
    for (int p = 0; p < 2; ++p) {
      int g = tid + (p << 8);
      int c = g >> 2, s = g & 3;
      *(bf16x8*)&Bh[sw(c, s)] = *(const bf16x8*)&Wh[(size_t)c * K + k0 + s * 8];
      *(bf16x8*)&Bl[sw(c, s)] = *(const bf16x8*)&Wl[(size_t)c * K + k0 + s * 8];
    }
    __syncthreads();

    bf16x8 ah[2], al[2];
#pragma unroll
    for (int mi = 0; mi < 2; ++mi) {
      int r = wid * 32 + mi * 16 + lrow;
      ah[mi] = *(const bf16x8*)&Ah[sw(r, kg)];
      al[mi] = *(const bf16x8*)&Al[sw(r, kg)];
    }
#pragma unroll
    for (int ni = 0; ni < 8; ++ni) {
      int c = ni * 16 + lrow;
      bf16x8 bh = *(const bf16x8*)&Bh[sw(c, kg)];
      bf16x8 bl = *(const bf16x8*)&Bl[sw(c, kg)];
#pragma unroll
      for (int mi = 0; mi < 2; ++mi) {
        acc[mi][ni] = __builtin_amdgcn_mfma_f32_16x16x32_bf16(ah[mi], bh, acc[mi][ni], 0, 0, 0);
        acc[mi][ni] = __builtin_amdgcn_mfma_f32_16x16x32_bf16(al[mi], bh, acc[mi][ni], 0, 0, 0);
        acc[mi][ni] = __builtin_amdgcn_mfma_f32_16x16x32_bf16(ah[mi], bl, acc[mi][ni], 0, 0, 0);
      }
    }
    __syncthreads();
  }
  // epilogue: C frag row=(lane>>4)*4+reg, col=lane&15
#pragma unroll
  for (int mi = 0; mi < 2; ++mi)
#pragma unroll
    for (int ni = 0; ni < 8; ++ni)
#pragma unroll
      for (int r = 0; r < 4; ++r) {
        int grow = row0 + wid * 32 + mi * 16 + kg * 4 + r;
        if (grow < M) {
          float val = acc[mi][ni][r];
          Y[(size_t)grow * HID + ni * 16 + lrow] = val;
          Y16[(size_t)grow * HID + ni * 16 + lrow] = (_Float16)val;
        }
      }
}

// ---------------- gather-aggregate (fp16 neighbors) + bias + ReLU ----------
// One wave per node. 4 groups of 16 lanes; group g strides the neighbor list
// by 4, each lane loading 8 fp16 features (16 B) -> 4 rows (1 KB) in flight
// per wave-iteration. Self term from fp32. fp32 accumulate throughout.
__global__ __launch_bounds__(256) void k_agg16(const float* __restrict__ xw,
                                               const _Float16* __restrict__ xh,
                                               const float* __restrict__ dinv,
                                               const int* __restrict__ off,
                                               const int2* __restrict__ edata,
                                               const float* __restrict__ bias,
                                               float* __restrict__ hout, int n) {
  int v = blockIdx.x * 4 + (threadIdx.x >> 6);
  if (v >= n) return;
  int lane = threadIdx.x & 63;
  int grp = lane >> 4, gl = lane & 15;
  int fb = gl * 8;                       // this lane's 8 features
  float acc[8] = {0.f, 0.f, 0.f, 0.f, 0.f, 0.f, 0.f, 0.f};
  int j0 = off[v], j1 = off[v + 1];
  for (int j = j0 + grp; j < j1; j += 4) {
    int2 e = edata[j];
    float w = __int_as_float(e.y);
    f16x8 m = *(const f16x8*)&xh[(size_t)e.x * HID + fb];
#pragma unroll
    for (int q = 0; q < 8; ++q) acc[q] = fmaf(w, (float)m[q], acc[q]);
  }
  // combine the 4 groups (feature layout identical across groups)
#pragma unroll
  for (int q = 0; q < 8; ++q) {
    acc[q] += __shfl_xor(acc[q], 16);
    acc[q] += __shfl_xor(acc[q], 32);
  }
  if (grp == 0) {
    float dv = dinv[v], dv2 = dv * dv;
    const float4 s0 = *(const float4*)&xw[(size_t)v * HID + fb];
    const float4 s1 = *(const float4*)&xw[(size_t)v * HID + fb + 4];
    const float4 b0 = *(const float4*)&bias[fb];
    const float4 b1 = *(const float4*)&bias[fb + 4];
    float4 o0, o1;
    o0.x = fmaxf(fmaf(dv2, s0.x, acc[0]) + b0.x, 0.f);
    o0.y = fmaxf(fmaf(dv2, s0.y, acc[1]) + b0.y, 0.f);
    o0.z = fmaxf(fmaf(dv2, s0.z, acc[2]) + b0.z, 0.f);
    o0.w = fmaxf(fmaf(dv2, s0.w, acc[3]) + b0.w, 0.f);
    o1.x = fmaxf(fmaf(dv2, s1.x, acc[4]) + b1.x, 0.f);
    o1.y = fmaxf(fmaf(dv2, s1.y, acc[5]) + b1.y, 0.f);
    o1.z = fmaxf(fmaf(dv2, s1.z, acc[6]) + b1.z, 0.f);
    o1.w = fmaxf(fmaf(dv2, s1.w, acc[7]) + b1.w, 0.f);
    *(float4*)&hout[(size_t)v * HID + fb] = o0;
    *(float4*)&hout[(size_t)v * HID + fb + 4] = o1;
  }
}

// ---------------- per-graph node counts ----------------
__global__ __launch_bounds__(256) void k_gcnt(const idx_t* __restrict__ batch,
                                              int* __restrict__ gcnt, int n) {
  __shared__ int h[NGRAPH];
  int tid = threadIdx.x;
  if (tid < NGRAPH) h[tid] = 0;
  __syncthreads();
  int i = blockIdx.x * 256 + tid;
  if (i < n) atomicAdd(&h[batch[i]], 1);
  __syncthreads();
  if (tid < NGRAPH && h[tid]) atomicAdd(&gcnt[tid], h[tid]);
}

// ---------------- segment max+sum pooling (batch sorted) ----------------
__global__ __launch_bounds__(128) void k_pool(const float* __restrict__ h,
                                              const idx_t* __restrict__ batch,
                                              float* __restrict__ gmax,
                                              float* __restrict__ gsum, int n) {
  int f = threadIdx.x;
  int v0 = blockIdx.x * 128;
  int cur = -1;
  float mx = 0.f, sm = 0.f;
  for (int i = 0; i < 128; ++i) {
    int v = v0 + i;
    if (v >= n) break;
    int g = batch[v];
    if (g != cur) {
      if (cur >= 0) {
        atomicMax((int*)&gmax[cur * HID + f], __float_as_int(mx));  // h>=0
        atomicAdd(&gsum[cur * HID + f], sm);
      }
      cur = g; mx = 0.f; sm = 0.f;
    }
    float val = h[(size_t)v * HID + f];
    mx = fmaxf(mx, val);
    sm += val;
  }
  if (cur >= 0) {
    atomicMax((int*)&gmax[cur * HID + f], __float_as_int(mx));
    atomicAdd(&gsum[cur * HID + f], sm);
  }
}

// ---------------- tiny MLP head (one block) ----------------
__global__ __launch_bounds__(256) void k_mlp(const float* __restrict__ gmax,
                                             const float* __restrict__ gsum,
                                             const int* __restrict__ gcnt,
                                             const float* __restrict__ Wl1,
                                             const float* __restrict__ bl1,
                                             const float* __restrict__ Wl2,
                                             const float* __restrict__ bl2,
                                             const float* __restrict__ Wl3,
                                             const float* __restrict__ bl3,
                                             float* __restrict__ out) {
  __shared__ float G[NGRAPH][2 * HID];
  __shared__ float H1[NGRAPH][HID];
  __shared__ float H2[NGRAPH][HID / 2];
  int t = threadIdx.x;
  for (int i = t; i < NGRAPH * 2 * HID; i += 256) {
    int gi = i >> 8, j = i & 255;
    float val;
    if (j < HID) val = gmax[gi * HID + j];
    else val = gsum[gi * HID + (j - HID)] / fmaxf((float)gcnt[gi], 1.0f);
    G[gi][j] = val;
  }
  __syncthreads();
  for (int i = t; i < NGRAPH * HID; i += 256) {
    int gi = i >> 7, j = i & 127;
    float a = bl1[j];
    for (int k = 0; k < 2 * HID; ++k) a = fmaf(G[gi][k], Wl1[k * HID + j], a);
    H1[gi][j] = fmaxf(a, 0.f);
  }
  __syncthreads();
  {
    int gi = t >> 6, j = t & 63;
    float a = bl2[j];
    for (int k = 0; k < HID; ++k) a = fmaf(H1[gi][k], Wl2[k * 64 + j], a);
    H2[gi][j] = fmaxf(a, 0.f);
  }
  __syncthreads();
  if (t < NGRAPH) {
    float a = bl3[0];
    for (int k = 0; k < 64; ++k) a = fmaf(H2[t][k], Wl3[k], a);
    out[t] = fminf(a, 5.0f);
  }
}

extern "C" void kernel_launch(void* const* d_in, const int* in_sizes, int n_in,
                              void* d_out, int out_size, void* d_ws, size_t ws_size,
                              hipStream_t stream) {
  const float* x   = (const float*)d_in[0];
  const idx_t* ei  = (const idx_t*)d_in[1];
  const idx_t* bat = (const idx_t*)d_in[2];
  const float* W0 = (const float*)d_in[3];  const float* b0 = (const float*)d_in[4];
  const float* W1 = (const float*)d_in[5];  const float* b1 = (const float*)d_in[6];
  const float* W2 = (const float*)d_in[7];  const float* b2 = (const float*)d_in[8];
  const float* Wl1 = (const float*)d_in[9];  const float* bl1 = (const float*)d_in[10];
  const float* Wl2 = (const float*)d_in[11]; const float* bl2 = (const float*)d_in[12];
  const float* Wl3 = (const float*)d_in[13]; const float* bl3 = (const float*)d_in[14];
  float* out = (float*)d_out;

  const int N = in_sizes[2];
  const int E = in_sizes[1] / 2;
  const idx_t* srcv = ei;
  const idx_t* dstv = ei + E;
  const int nb = (N + SC - 1) / SC;  // 49 scan blocks (<=64)

  char* ws = (char*)d_ws;
  size_t o = 0;
  auto alloc = [&](size_t bytes) -> void* {
    void* p = ws + o;
    o = (o + bytes + 255) & ~(size_t)255;
    return p;
  };
  float* bufA      = (float*)alloc((size_t)N * HID * 4);      // xw fp32
  _Float16* bufA16 = (_Float16*)alloc((size_t)N * HID * 2);   // xw fp16
  float* bufB      = (float*)alloc((size_t)N * HID * 4);      // h fp32
  float* dinv = (float*)alloc((size_t)N * 4);
  int* cnt    = (int*)alloc((size_t)N * 4);
  int* off    = (int*)alloc((size_t)(N + 1) * 4);
  int* fillc  = (int*)alloc((size_t)N * 4);
  int2* edata = (int2*)alloc((size_t)E * 8);
  int* bsum   = (int*)alloc(64 * 4);
  int* boff   = (int*)alloc(64 * 4);
  ushort* Wh0 = (ushort*)alloc((size_t)1024 * HID * 2);
  ushort* Wl0 = (ushort*)alloc((size_t)1024 * HID * 2);
  ushort* Wh1 = (ushort*)alloc((size_t)HID * HID * 2);
  ushort* Wlo1 = (ushort*)alloc((size_t)HID * HID * 2);
  ushort* Wh2 = (ushort*)alloc((size_t)HID * HID * 2);
  ushort* Wlo2 = (ushort*)alloc((size_t)HID * HID * 2);
  float* gmax = (float*)alloc(NGRAPH * HID * 4);
  float* gsum = (float*)alloc(NGRAPH * HID * 4);
  int* gcnt   = (int*)alloc(NGRAPH * 4);

  hipMemsetAsync(cnt, 0, (size_t)N * 4, stream);
  hipMemsetAsync(fillc, 0, (size_t)N * 4, stream);
  hipMemsetAsync(gmax, 0, NGRAPH * HID * 4, stream);
  hipMemsetAsync(gsum, 0, NGRAPH * HID * 4, stream);
  hipMemsetAsync(gcnt, 0, NGRAPH * 4, stream);

  // weight splits (tiny)
  k_wsplit<<<(1024 * HID + 255) / 256, 256, 0, stream>>>(W0, Wh0, Wl0, 1024);
  k_wsplit<<<(HID * HID + 255) / 256, 256, 0, stream>>>(W1, Wh1, Wlo1, HID);
  k_wsplit<<<(HID * HID + 255) / 256, 256, 0, stream>>>(W2, Wh2, Wlo2, HID);

  // CSR build
  k_count<<<(E + 255) / 256, 256, 0, stream>>>(dstv, cnt, E);
  k_scan1<<<nb, 256, 0, stream>>>(cnt, bsum, N);
  k_scan2<<<1, 64, 0, stream>>>(bsum, boff, off, nb, N);
  k_scan3<<<nb, 256, 0, stream>>>(cnt, boff, off, dinv, N);
  k_fill<<<(E + 255) / 256, 256, 0, stream>>>(srcv, dstv, off, dinv, fillc, edata, E);

  const int gblk = (N + 127) / 128;
  const int ablk = (N + 3) / 4;
  // layer 0: 1024 -> 128
  k_gemm_mfma<1024><<<gblk, 256, 0, stream>>>(x, Wh0, Wl0, bufA, bufA16, N);
  k_agg16<<<ablk, 256, 0, stream>>>(bufA, bufA16, dinv, off, edata, b0, bufB, N);
  // layer 1
  k_gemm_mfma<HID><<<gblk, 256, 0, stream>>>(bufB, Wh1, Wlo1, bufA, bufA16, N);
  k_agg16<<<ablk, 256, 0, stream>>>(bufA, bufA16, dinv, off, edata, b1, bufB, N);
  // layer 2
  k_gemm_mfma<HID><<<gblk, 256, 0, stream>>>(bufB, Wh2, Wlo2, bufA, bufA16, N);
  k_agg16<<<ablk, 256, 0, stream>>>(bufA, bufA16, dinv, off, edata, b2, bufB, N);

  // pooling + head
  k_gcnt<<<(N + 255) / 256, 256, 0, stream>>>(bat, gcnt, N);
  k_pool<<<(N + 127) / 128, 128, 0, stream>>>(bufB, bat, gmax, gsum, N);
  k_mlp<<<1, 256, 0, stream>>>(gmax, gsum, gcnt, Wl1, bl1, Wl2, bl2, Wl3, bl3, out);
}